// Round 11
// baseline (1298.164 us; speedup 1.0000x reference)
//
#include <hip/hip_runtime.h>

#define B_ 64
#define S_ 2048
#define D_ 64
#define H_ 128
#define G_ 512
#define CH 16

typedef float f32x4 __attribute__((ext_vector_type(4)));
typedef short bf16x8 __attribute__((ext_vector_type(8)));
typedef short short2v __attribute__((ext_vector_type(2)));
typedef _Float16 half2v __attribute__((ext_vector_type(2)));

#define MFMA16(a, b, c) __builtin_amdgcn_mfma_f32_16x16x32_bf16((a), (b), (c), 0, 0, 0)
#define RCPF(x) __builtin_amdgcn_rcpf(x)
#define LOG2E 1.442695041f

#if __has_builtin(__builtin_amdgcn_exp2f)
#define EXP2(x) __builtin_amdgcn_exp2f(x)
#else
#define EXP2(x) exp2f(x)
#endif

// v_dot2_f32_f16: 2 f16 MACs + f32 accumulate per instr -> recurrence issue
// cost 128 instr/SIMD/step (~256cy), half the MFMA-matvec floor (512cy).
#if __has_builtin(__builtin_amdgcn_fdot2)
#define DOT2(a, b, c) __builtin_amdgcn_fdot2((a), (b), (c), false)
#else
__device__ __forceinline__ float DOT2(half2v a, half2v b, float c) {
    return __builtin_fmaf((float)a[1], (float)b[1],
           __builtin_fmaf((float)a[0], (float)b[0], c));
}
#endif

// Per-step barrier: drain LDS, HW barrier, zero-cost compiler memory fence.
// (R7/R8/R9-proven; keeps global prefetch in flight, no scheduler pinning.)
#define STEP_SYNC() do {                                  \
    asm volatile("s_waitcnt lgkmcnt(0)" ::: "memory");    \
    __builtin_amdgcn_s_barrier();                         \
    asm volatile("" ::: "memory");                        \
} while (0)

__device__ __forceinline__ short f2bf(float f) {
    unsigned u = __builtin_bit_cast(unsigned, f);
    return (short)((u + 0x7FFFu + ((u >> 16) & 1u)) >> 16);  // RNE
}
__device__ __forceinline__ short f2h(float f) {             // f16 bits in a short
    return __builtin_bit_cast(short, (_Float16)f);
}
__device__ __forceinline__ float h2f(short s) {
    return (float)__builtin_bit_cast(_Float16, s);
}
__device__ __forceinline__ float sigm_f(float x) { return RCPF(1.0f + EXP2(x * -LOG2E)); }

// One block per batch element; 512 threads = 8 waves.
// COLUMN-PER-THREAD recurrence (R10 idea, proven primitives only): lane l of
// wave w owns gate q = l&3 of hidden unit u = w*16 + (l>>2), i.e. column
// col = q*128+u of Wh. Per step: z[col] via 64 v_dot2 (prescaled f16 Wh
// column in 64 VGPRs, h broadcast-read from LDS), unified activation
// t = a*rcp(1+exp2(z))+b, quad rejoin via 3 __shfl_xor + selects (all quad
// lanes compute bitwise-identical c,h), lane q==0 writes h (f16) to the ring.
// MFMA only for the chunk xz-GEMM (M=16 fully used, boundary-only, R9 code).
__launch_bounds__(512, 2)
__global__ void lstm_fused(const float* __restrict__ x, const float* __restrict__ Wx,
                           const float* __restrict__ Wh, const float* __restrict__ bias,
                           const float* __restrict__ Wd, const float* __restrict__ bd,
                           float* __restrict__ out) {
    const int tid = threadIdx.x;
    const int lane = tid & 63;
    const int wid = tid >> 6;      // 0..7
    const int l15 = lane & 15;     // MFMA fragment col (xz GEMM only)
    const int l4 = lane >> 4;      // MFMA fragment row group (xz GEMM only)
    const int bb = blockIdx.x;

    const int q = lane & 3;                 // gate (i,f,g~,o)
    const int u = wid * 16 + (lane >> 2);   // hidden unit owned by this quad
    const int col = q * H_ + u;             // Wh column

    __shared__ alignas(16) short hist[CH][H_];   // h ring (f16 bits), slot = t & 15
    __shared__ alignas(16) short xbf[CH][72];    // x chunk (bf16, padded)
    __shared__ alignas(16) float xzc[CH][G_];    // [tm][unit*4+gate], prescaled

    // zero hist: 16*128 shorts = 1024 dwords (f16 zero == 0x0000)
    ((unsigned*)hist)[tid] = 0u;
    ((unsigned*)hist)[tid + 512] = 0u;

    const float msc = (q == 2) ? (-2.0f * LOG2E) : (-LOG2E);
    const float a_c = (q == 2) ? 2.0f : 1.0f;
    const float b_c = (q == 2) ? -1.0f : 0.0f;

    // --- per-thread Wh column, prescaled, f16-packed: 64 half2 = 64 VGPRs ---
    half2v wh[64];
#pragma unroll
    for (int p = 0; p < 64; ++p) {
        half2v v;
        v[0] = (_Float16)(Wh[(2 * p + 0) * G_ + col] * msc);
        v[1] = (_Float16)(Wh[(2 * p + 1) * G_ + col] * msc);
        wh[p] = v;
    }

    // --- MFMA B-fragments for the xz GEMM (prescaled per gate ct; R9 code) ---
    bf16x8 bx[4][2];
#pragma unroll
    for (int ct = 0; ct < 4; ++ct) {
        const float ms = (ct == 2) ? (-2.0f * LOG2E) : (-LOG2E);
        const int colm = ct * H_ + wid * 16 + l15;
#pragma unroll
        for (int kt = 0; kt < 2; ++kt) {
            bf16x8 v;
#pragma unroll
            for (int e = 0; e < 8; ++e)
                v[e] = f2bf(Wx[(kt * 32 + l4 * 8 + e) * G_ + colm] * ms);
            bx[ct][kt] = v;
        }
    }
    float bvr[4];
#pragma unroll
    for (int ct = 0; ct < 4; ++ct)
        bvr[ct] = bias[ct * H_ + wid * 16 + l15] *
                  ((ct == 2) ? (-2.0f * LOG2E) : (-LOG2E));

    const float wd0 = Wd[lane * 2 + 0];
    const float wd1 = Wd[lane * 2 + 1];
    const float bdv = bd[0];
    float c_reg = 0.0f;   // bitwise-identical across each quad at every step

    const float* xb = x + (size_t)bb * S_ * D_;
    float* ob = out + (size_t)bb * S_;

    float xp0 = xb[tid * 2 + 0];
    float xp1 = xb[tid * 2 + 1];

    const bool sb0 = (q & 1) != 0;
    const bool sb1 = (q & 2) != 0;

    for (int tc = 0; tc < S_; tc += CH) {
        // commit prefetched x chunk (data dep forces the vmcnt wait here)
        xbf[tid >> 5][(tid & 31) * 2 + 0] = f2bf(xp0);
        xbf[tid >> 5][(tid & 31) * 2 + 1] = f2bf(xp1);
        __syncthreads();
        if (tc + CH < S_) {
            xp0 = xb[(tc + CH) * D_ + tid * 2 + 0];
            xp1 = xb[(tc + CH) * D_ + tid * 2 + 1];
        }
        // xz_chunk = X[16x64] @ Wx + b (prescaled) -> layout [tm][unit*4+gate]
#pragma unroll
        for (int ct = 0; ct < 4; ++ct) {
            f32x4 cc = {bvr[ct], bvr[ct], bvr[ct], bvr[ct]};
#pragma unroll
            for (int kt = 0; kt < 2; ++kt) {
                const bf16x8 a = *reinterpret_cast<const bf16x8*>(&xbf[l15][kt * 32 + l4 * 8]);
                cc = MFMA16(a, bx[ct][kt], cc);
            }
#pragma unroll
            for (int r = 0; r < 4; ++r)
                xzc[l4 * 4 + r][(wid * 16 + l15) * 4 + ct] = cc[r];  // D row=(lane>>4)*4+r [m89]
        }
        // dense head for the PREVIOUS chunk (hist = h_{tc-16..tc-1})
        if (tc > 0) {
#pragma unroll
            for (int s = 0; s < 2; ++s) {
                const int row = wid * 2 + s;
                const short2v hp = *reinterpret_cast<const short2v*>(&hist[row][lane * 2]);
                float p = h2f(hp[0]) * wd0 + h2f(hp[1]) * wd1;
                p += __shfl_xor(p, 1);  p += __shfl_xor(p, 2);  p += __shfl_xor(p, 4);
                p += __shfl_xor(p, 8);  p += __shfl_xor(p, 16); p += __shfl_xor(p, 32);
                if (lane == 0) ob[tc - CH + row] = sigm_f(p + bdv);
            }
        }
        __syncthreads();   // xzc ready; hist fully consumed before overwrite

#pragma unroll
        for (int tm = 0; tm < CH; ++tm) {
            const int prev = (tm + CH - 1) & (CH - 1);
            const short* hsrc = hist[prev];

            // z = prescaled xz (C-init) + h . Wh_col via 4 interleaved dot2 chains
            float za = xzc[tm][u * 4 + q], zb = 0.0f, zc2 = 0.0f, zd = 0.0f;
#pragma unroll
            for (int j = 0; j < 16; ++j) {
                // broadcast read: all lanes same address -> conflict-free
                const bf16x8 hr = *reinterpret_cast<const bf16x8*>(&hsrc[j * 8]);
                const short2v s0 = {hr[0], hr[1]};
                const short2v s1 = {hr[2], hr[3]};
                const short2v s2 = {hr[4], hr[5]};
                const short2v s3 = {hr[6], hr[7]};
                za  = DOT2(__builtin_bit_cast(half2v, s0), wh[j * 4 + 0], za);
                zb  = DOT2(__builtin_bit_cast(half2v, s1), wh[j * 4 + 1], zb);
                zc2 = DOT2(__builtin_bit_cast(half2v, s2), wh[j * 4 + 2], zc2);
                zd  = DOT2(__builtin_bit_cast(half2v, s3), wh[j * 4 + 3], zd);
            }
            const float z = (za + zb) + (zc2 + zd);   // prescaled pre-activation

            // unified activation for this lane's gate
            const float t = __builtin_fmaf(a_c, RCPF(1.0f + EXP2(z)), b_c);

            // quad rejoin via PROVEN shfl_xor: lane q holds gates (q,q^1,q^2,q^3)
            const float t1 = __shfl_xor(t, 1);
            const float t2 = __shfl_xor(t, 2);
            const float t3 = __shfl_xor(t, 3);
            const float ig = sb0 ? (t1 * t3) : (t * t2);            // i * g~
            const float fv = sb0 ? (sb1 ? t2 : t) : (sb1 ? t3 : t1); // f
            const float ov = sb0 ? (sb1 ? t : t2) : (sb1 ? t1 : t3); // o

            c_reg = __builtin_fmaf(fv, c_reg, ig);
            const float th = __builtin_fmaf(
                2.0f, RCPF(1.0f + EXP2(c_reg * (-2.0f * LOG2E))), -1.0f);
            const float hv = ov * th;

            if (q == 0) hist[tm][u] = f2h(hv);   // one writer per unit
            STEP_SYNC();   // h_t visible to all waves for step t+1
        }
    }

    // dense head for the final 16 steps
#pragma unroll
    for (int s = 0; s < 2; ++s) {
        const int row = wid * 2 + s;
        const short2v hp = *reinterpret_cast<const short2v*>(&hist[row][lane * 2]);
        float p = h2f(hp[0]) * wd0 + h2f(hp[1]) * wd1;
        p += __shfl_xor(p, 1);  p += __shfl_xor(p, 2);  p += __shfl_xor(p, 4);
        p += __shfl_xor(p, 8);  p += __shfl_xor(p, 16); p += __shfl_xor(p, 32);
        if (lane == 0) ob[S_ - CH + row] = sigm_f(p + bdv);
    }
}

extern "C" void kernel_launch(void* const* d_in, const int* in_sizes, int n_in,
                              void* d_out, int out_size, void* d_ws, size_t ws_size,
                              hipStream_t stream) {
    const float* x  = (const float*)d_in[0];
    const float* Wx = (const float*)d_in[1];
    const float* Wh = (const float*)d_in[2];
    const float* b  = (const float*)d_in[3];
    const float* Wd = (const float*)d_in[4];
    const float* bd = (const float*)d_in[5];
    float* out = (float*)d_out;

    lstm_fused<<<B_, 512, 0, stream>>>(x, Wx, Wh, b, Wd, bd, out);
}